// Round 1
// baseline (169.727 us; speedup 1.0000x reference)
//
#include <hip/hip_runtime.h>
#include <hip/hip_bf16.h>

#define B_ 4096
#define F_ 8
#define V_ 1000
#define D_ 1024
#define VP 1024  // V padded to tile multiple

#define BM 128
#define BN 128
#define BK 32

typedef __bf16 bf16x8 __attribute__((ext_vector_type(8)));
typedef float f32x4 __attribute__((ext_vector_type(4)));

__device__ __forceinline__ void gload_lds16(const void* g, void* l) {
  __builtin_amdgcn_global_load_lds(
      (const __attribute__((address_space(1))) void*)g,
      (__attribute__((address_space(3))) void*)l, 16, 0, 0);
}

// ---------------------------------------------------------------------------
// Kernel 0: W (F,D,V) f32  ->  Wt (F, VP, D) bf16, zero-padded rows v in [V,VP)
// ---------------------------------------------------------------------------
__global__ __launch_bounds__(256) void transpose_w(
    const float* __restrict__ W, __hip_bfloat16* __restrict__ Wt) {
  __shared__ float tile[32][33];
  const int f = blockIdx.z;
  const int k0 = blockIdx.x * 32;
  const int v0 = blockIdx.y * 32;
  const int tx = threadIdx.x;  // 32
  const int ty = threadIdx.y;  // 8
  const float* Wf = W + (size_t)f * D_ * V_;
#pragma unroll
  for (int i = 0; i < 4; ++i) {
    int k = k0 + ty + i * 8;
    int v = v0 + tx;
    tile[ty + i * 8][tx] = (v < V_) ? Wf[k * V_ + v] : 0.0f;
  }
  __syncthreads();
  __hip_bfloat16* Wtf = Wt + (size_t)f * VP * D_;
#pragma unroll
  for (int i = 0; i < 4; ++i) {
    int v = v0 + ty + i * 8;
    int k = k0 + tx;
    Wtf[v * D_ + k] = __float2bfloat16(tile[tx][ty + i * 8]);
  }
}

// ---------------------------------------------------------------------------
// Kernel 1: fused gather + cumsum + LayerNorm + exact gelu -> H (F, B, D) bf16
// One block per batch row b; 256 threads x 4 floats = D.
// ---------------------------------------------------------------------------
__global__ __launch_bounds__(256) void fuse_h(
    const float* __restrict__ emb, const int* __restrict__ feats,
    const float* __restrict__ tables, const float* __restrict__ gamma,
    const float* __restrict__ beta, __hip_bfloat16* __restrict__ H) {
  const int b = blockIdx.x;
  const int t = threadIdx.x;
  const int d = t * 4;
  const int wave = t >> 6, lane = t & 63;

  float s[4];
  {
    float4 v = *reinterpret_cast<const float4*>(&emb[(size_t)b * D_ + d]);
    s[0] = v.x; s[1] = v.y; s[2] = v.z; s[3] = v.w;
  }
  float gm[4], bt[4];
  {
    float4 g = *reinterpret_cast<const float4*>(&gamma[d]);
    float4 bb = *reinterpret_cast<const float4*>(&beta[d]);
    gm[0] = g.x; gm[1] = g.y; gm[2] = g.z; gm[3] = g.w;
    bt[0] = bb.x; bt[1] = bb.y; bt[2] = bb.z; bt[3] = bb.w;
  }
  __shared__ float red[4][2];

  for (int f = 0; f < F_; ++f) {
    float sum = s[0] + s[1] + s[2] + s[3];
    float ssq = s[0] * s[0] + s[1] * s[1] + s[2] * s[2] + s[3] * s[3];
#pragma unroll
    for (int off = 32; off > 0; off >>= 1) {
      sum += __shfl_xor(sum, off, 64);
      ssq += __shfl_xor(ssq, off, 64);
    }
    if (lane == 0) { red[wave][0] = sum; red[wave][1] = ssq; }
    __syncthreads();
    sum = red[0][0] + red[1][0] + red[2][0] + red[3][0];
    ssq = red[0][1] + red[1][1] + red[2][1] + red[3][1];
    __syncthreads();  // red reused next iteration

    const float mu = sum * (1.0f / D_);
    const float var = ssq * (1.0f / D_) - mu * mu;
    const float rstd = rsqrtf(var + 1e-5f);

    __hip_bfloat16 hb[4];
#pragma unroll
    for (int j = 0; j < 4; ++j) {
      float x = (s[j] - mu) * rstd * gm[j] + bt[j];
      float g = 0.5f * x * (1.0f + erff(x * 0.70710678118654752f));
      hb[j] = __float2bfloat16(g);
    }
    *reinterpret_cast<uint2*>(&H[(size_t)f * (B_ * D_) + (size_t)b * D_ + d]) =
        *reinterpret_cast<const uint2*>(hb);

    if (f < F_ - 1) {
      int feat = feats[b * F_ + f];
      const float* row = tables + ((size_t)f * V_ + feat) * D_;
      float4 tv = *reinterpret_cast<const float4*>(&row[d]);
      s[0] += tv.x; s[1] += tv.y; s[2] += tv.z; s[3] += tv.w;
    }
  }
}

// ---------------------------------------------------------------------------
// Kernel 2: per-f GEMM  out[b, f, v] = sum_k H[f,b,k] * Wt[f,v,k] + bias[f,v]
// 128x128 tile, BK=32, 4 waves (2x2), 16x16x32 bf16 MFMA.
// global_load_lds width=16 staging; XOR slot-swizzle via pre-swizzled global
// source (LDS linear), slot' = slot ^ ((row>>1)&3) on ds_read side.
// ---------------------------------------------------------------------------
__global__ __launch_bounds__(256, 2) void gemm_hw(
    const ushort* __restrict__ H,    // (F, B, D) bf16
    const ushort* __restrict__ Wt,   // (F, VP, D) bf16
    const float* __restrict__ bias,  // (F, V)
    float* __restrict__ out) {       // (B, F, V)
  __shared__ ushort As[BM * BK];  // 8 KB
  __shared__ ushort Bs[BN * BK];  // 8 KB

  const int f = blockIdx.y;
  const int mt = blockIdx.x >> 3;  // 32 m-tiles
  const int nt = blockIdx.x & 7;   // 8 n-tiles
  const int t = threadIdx.x;
  const int w = t >> 6, l = t & 63;
  const int wm = w >> 1, wn = w & 1;

  const ushort* Hf = H + (size_t)f * (B_ * D_);
  const ushort* Wtf = Wt + (size_t)f * (VP * D_);

  // staging: each wave DMAs 2 chunks of 1024B for A and B.
  // lane l of chunk c lands at LDS row (w*2+c)*16 + l/4, slot l&3.
  // pre-swizzle: fetch global slot  s = (l&3) ^ ((l>>3)&3).
  const int sgl = (l & 3) ^ ((l >> 3) & 3);
  const int row0 = (w * 2) * 16 + (l >> 2);
  const ushort* gA0 = Hf + (size_t)(mt * BM + row0) * D_ + sgl * 8;
  const ushort* gA1 = gA0 + 16 * D_;
  const ushort* gB0 = Wtf + (size_t)(nt * BN + row0) * D_ + sgl * 8;
  const ushort* gB1 = gB0 + 16 * D_;
  ushort* lA0 = &As[(w * 2) * 512];
  ushort* lA1 = &As[(w * 2 + 1) * 512];
  ushort* lB0 = &Bs[(w * 2) * 512];
  ushort* lB1 = &Bs[(w * 2 + 1) * 512];

  // fragment ds_read offsets (elements), swizzled slot
  int rA[4], rB[4];
#pragma unroll
  for (int i = 0; i < 4; ++i) {
    int r = wm * 64 + i * 16 + (l & 15);
    int sl = (l >> 4) ^ ((r >> 1) & 3);
    rA[i] = r * BK + sl * 8;
    int rn = wn * 64 + i * 16 + (l & 15);
    int sln = (l >> 4) ^ ((rn >> 1) & 3);
    rB[i] = rn * BK + sln * 8;
  }

  f32x4 acc[4][4] = {};

  for (int kt = 0; kt < D_ / BK; ++kt) {
    const int ko = kt * BK;
    gload_lds16(gA0 + ko, lA0);
    gload_lds16(gA1 + ko, lA1);
    gload_lds16(gB0 + ko, lB0);
    gload_lds16(gB1 + ko, lB1);
    __syncthreads();  // compiler drains vmcnt before barrier

    bf16x8 af[4], bfr[4];
#pragma unroll
    for (int i = 0; i < 4; ++i) {
      af[i] = *reinterpret_cast<const bf16x8*>(&As[rA[i]]);
      bfr[i] = *reinterpret_cast<const bf16x8*>(&Bs[rB[i]]);
    }
#pragma unroll
    for (int i = 0; i < 4; ++i)
#pragma unroll
      for (int j = 0; j < 4; ++j)
        acc[i][j] = __builtin_amdgcn_mfma_f32_16x16x32_bf16(
            af[i], bfr[j], acc[i][j], 0, 0, 0);
    __syncthreads();  // LDS reads done before next-iter DMA overwrite
  }

  // epilogue: C layout col = lane&15, row = (lane>>4)*4 + q  (m89-verified)
  const float* bf_ = bias + f * V_;
  const int crow0 = mt * BM + wm * 64 + ((l >> 4) << 2);
  const int ccol0 = nt * BN + wn * 64 + (l & 15);
#pragma unroll
  for (int i = 0; i < 4; ++i) {
#pragma unroll
    for (int j = 0; j < 4; ++j) {
      int col = ccol0 + j * 16;
      if (col < V_) {
        float bb = bf_[col];
        int row = crow0 + i * 16;
        float* op = out + (size_t)row * (F_ * V_) + (size_t)f * V_ + col;
#pragma unroll
        for (int q = 0; q < 4; ++q)
          op[(size_t)q * (F_ * V_)] = acc[i][j][q] + bb;
      }
    }
  }
}

// ---------------------------------------------------------------------------
extern "C" void kernel_launch(void* const* d_in, const int* in_sizes, int n_in,
                              void* d_out, int out_size, void* d_ws,
                              size_t ws_size, hipStream_t stream) {
  const float* emb = (const float*)d_in[0];     // (B, D)
  const int* feats = (const int*)d_in[1];       // (B, F)
  const float* tables = (const float*)d_in[2];  // (F, V, D)
  const float* gamma = (const float*)d_in[3];   // (D,)
  const float* beta = (const float*)d_in[4];    // (D,)
  const float* W = (const float*)d_in[5];       // (F, D, V)
  const float* bias = (const float*)d_in[6];    // (F, V)
  float* out = (float*)d_out;                   // (B, F, V)

  char* ws = (char*)d_ws;
  __hip_bfloat16* Hbuf = (__hip_bfloat16*)ws;  // F*B*D*2 = 64 MiB
  __hip_bfloat16* Wtbuf =
      (__hip_bfloat16*)(ws + (size_t)F_ * B_ * D_ * 2);  // F*VP*D*2 = 16 MiB

  transpose_w<<<dim3(D_ / 32, VP / 32, F_), dim3(32, 8), 0, stream>>>(W, Wtbuf);
  fuse_h<<<dim3(B_), dim3(256), 0, stream>>>(emb, feats, tables, gamma, beta,
                                             Hbuf);
  gemm_hw<<<dim3((B_ / BM) * (VP / BN), F_), dim3(256), 0, stream>>>(
      (const ushort*)Hbuf, (const ushort*)Wtbuf, bias, out);
}

// Round 2
// 136.448 us; speedup vs baseline: 1.2439x; 1.2439x over previous
//
#include <hip/hip_runtime.h>
#include <hip/hip_bf16.h>

#define B_ 4096
#define F_ 8
#define V_ 1000
#define D_ 1024
#define VP 1024

typedef __bf16 bf16x8 __attribute__((ext_vector_type(8)));
typedef float f32x4 __attribute__((ext_vector_type(4)));

__device__ __forceinline__ void gload_lds16(const void* g, void* l) {
  __builtin_amdgcn_global_load_lds(
      (const __attribute__((address_space(1))) void*)g,
      (__attribute__((address_space(3))) void*)l, 16, 0, 0);
}

__device__ __forceinline__ void phase_barrier() {
  __builtin_amdgcn_sched_barrier(0);
  __builtin_amdgcn_s_barrier();
  __builtin_amdgcn_sched_barrier(0);
}

// ---------------------------------------------------------------------------
// Kernel 0: W (F,D,V) f32 -> Wt (F, VP, D) bf16, zero-padded v in [V,VP)
// ---------------------------------------------------------------------------
__global__ __launch_bounds__(256) void transpose_w(
    const float* __restrict__ W, __hip_bfloat16* __restrict__ Wt) {
  __shared__ float tile[32][33];
  const int f = blockIdx.z;
  const int k0 = blockIdx.x * 32;
  const int v0 = blockIdx.y * 32;
  const int tx = threadIdx.x;
  const int ty = threadIdx.y;
  const float* Wf = W + (size_t)f * D_ * V_;
#pragma unroll
  for (int i = 0; i < 4; ++i) {
    int k = k0 + ty + i * 8;
    int v = v0 + tx;
    tile[ty + i * 8][tx] = (v < V_) ? Wf[k * V_ + v] : 0.0f;
  }
  __syncthreads();
  __hip_bfloat16* Wtf = Wt + (size_t)f * VP * D_;
#pragma unroll
  for (int i = 0; i < 4; ++i) {
    int v = v0 + ty + i * 8;
    int k = k0 + tx;
    Wtf[v * D_ + k] = __float2bfloat16(tile[tx][ty + i * 8]);
  }
}

// ---------------------------------------------------------------------------
// Kernel 1: fused gather + cumsum + LayerNorm + exact gelu -> H (F, B, D) bf16
// ---------------------------------------------------------------------------
__global__ __launch_bounds__(256) void fuse_h(
    const float* __restrict__ emb, const int* __restrict__ feats,
    const float* __restrict__ tables, const float* __restrict__ gamma,
    const float* __restrict__ beta, __hip_bfloat16* __restrict__ H) {
  const int b = blockIdx.x;
  const int t = threadIdx.x;
  const int d = t * 4;
  const int wave = t >> 6, lane = t & 63;

  float s[4];
  {
    float4 v = *reinterpret_cast<const float4*>(&emb[(size_t)b * D_ + d]);
    s[0] = v.x; s[1] = v.y; s[2] = v.z; s[3] = v.w;
  }
  float gm[4], bt[4];
  {
    float4 g = *reinterpret_cast<const float4*>(&gamma[d]);
    float4 bb = *reinterpret_cast<const float4*>(&beta[d]);
    gm[0] = g.x; gm[1] = g.y; gm[2] = g.z; gm[3] = g.w;
    bt[0] = bb.x; bt[1] = bb.y; bt[2] = bb.z; bt[3] = bb.w;
  }
  __shared__ float red[4][2];

  for (int f = 0; f < F_; ++f) {
    float sum = s[0] + s[1] + s[2] + s[3];
    float ssq = s[0] * s[0] + s[1] * s[1] + s[2] * s[2] + s[3] * s[3];
#pragma unroll
    for (int off = 32; off > 0; off >>= 1) {
      sum += __shfl_xor(sum, off, 64);
      ssq += __shfl_xor(ssq, off, 64);
    }
    if (lane == 0) { red[wave][0] = sum; red[wave][1] = ssq; }
    __syncthreads();
    sum = red[0][0] + red[1][0] + red[2][0] + red[3][0];
    ssq = red[0][1] + red[1][1] + red[2][1] + red[3][1];
    __syncthreads();

    const float mu = sum * (1.0f / D_);
    const float var = ssq * (1.0f / D_) - mu * mu;
    const float rstd = rsqrtf(var + 1e-5f);

    __hip_bfloat16 hb[4];
#pragma unroll
    for (int j = 0; j < 4; ++j) {
      float x = (s[j] - mu) * rstd * gm[j] + bt[j];
      float g = 0.5f * x * (1.0f + erff(x * 0.70710678118654752f));
      hb[j] = __float2bfloat16(g);
    }
    *reinterpret_cast<uint2*>(&H[(size_t)f * (B_ * D_) + (size_t)b * D_ + d]) =
        *reinterpret_cast<const uint2*>(hb);

    if (f < F_ - 1) {
      int feat = feats[b * F_ + f];
      const float* row = tables + ((size_t)f * V_ + feat) * D_;
      float4 tv = *reinterpret_cast<const float4*>(&row[d]);
      s[0] += tv.x; s[1] += tv.y; s[2] += tv.z; s[3] += tv.w;
    }
  }
}

// ---------------------------------------------------------------------------
// Kernel 2: 256x256 8-phase GEMM, BK=64, 8 waves (2Mx4N), dbuf LDS, st_16x32
// swizzle via pre-swizzled global source + swizzled ds_read, counted vmcnt.
// out[b, f, v] = sum_k H[f,b,k] * Wt[f,v,k] + bias[f,v]
// ---------------------------------------------------------------------------
#define AOFF 0
#define BOFF 32768

#define STAGE(OPB, GB, DBUF, HALF, KT)                                        \
  do {                                                                        \
    const ushort* _g = (GB) + (size_t)(HALF) * (128 * D_) + (size_t)(KT) * 64;\
    ushort* _l = &lds[(OPB) + ((DBUF)*2 + (HALF)) * 8192 + w * 512];          \
    gload_lds16(_g, _l);                                                      \
    gload_lds16(_g + 64 * D_, _l + 4096);                                     \
  } while (0)

#define LD_A(DST, LBASE, FIOFF)                                               \
  _Pragma("unroll") for (int _fj = 0; _fj < 4; ++_fj)                         \
  _Pragma("unroll") for (int _ks = 0; _ks < 2; ++_ks)                         \
      DST[_fj][_ks] = *reinterpret_cast<const bf16x8*>(                       \
          (LBASE) + ((((FIOFF) + _fj) * 2 + _ks) * 512));

#define LD_B(DST, LBASE, NFOFF)                                               \
  _Pragma("unroll") for (int _fn = 0; _fn < 2; ++_fn)                         \
  _Pragma("unroll") for (int _ks = 0; _ks < 2; ++_ks)                         \
      DST[_fn][_ks] = *reinterpret_cast<const bf16x8*>(                       \
          (LBASE) + ((((NFOFF) + _fn) * 2 + _ks) * 512));

#define Q_MFMA(AF, BF, R0, C0)                                                \
  do {                                                                        \
    __builtin_amdgcn_s_setprio(1);                                            \
    _Pragma("unroll") for (int _fj = 0; _fj < 4; ++_fj)                       \
    _Pragma("unroll") for (int _fn = 0; _fn < 2; ++_fn)                       \
    _Pragma("unroll") for (int _ks = 0; _ks < 2; ++_ks)                       \
        acc[(R0) + _fj][(C0) + _fn] =                                         \
            __builtin_amdgcn_mfma_f32_16x16x32_bf16(                          \
                AF[_fj][_ks], BF[_fn][_ks], acc[(R0) + _fj][(C0) + _fn],      \
                0, 0, 0);                                                     \
    __builtin_amdgcn_s_setprio(0);                                            \
  } while (0)

#define WAITV4 asm volatile("s_waitcnt vmcnt(4)" ::: "memory")
#define WAITV0 asm volatile("s_waitcnt vmcnt(0)" ::: "memory")

__global__ __launch_bounds__(512, 2) void gemm_hw(
    const ushort* __restrict__ H,    // (F, B, D) bf16
    const ushort* __restrict__ Wt,   // (F, VP, D) bf16
    const float* __restrict__ bias,  // (F, V)
    float* __restrict__ out) {       // (B, F, V)
  __shared__ ushort lds[65536];  // 128 KiB: A halves [0,32768), B [32768,65536)

  // bijective XCD swizzle: nwg=512, 512%8==0
  const int bid = blockIdx.x;
  const int swz = (bid & 7) * 64 + (bid >> 3);
  const int f = swz >> 6;
  const int r = swz & 63;
  const int mt = r >> 2, nt = r & 3;

  const int t = threadIdx.x;
  const int w = t >> 6, l = t & 63;
  const int wm = w >> 2;   // 0..1 (M)
  const int wn = w & 3;    // 0..3 (N)

  const ushort* Hf = H + (size_t)f * (B_ * D_);
  const ushort* Wf = Wt + (size_t)f * (VP * D_);

  // staging global source (pre-swizzled so linear LDS write = st_16x32 layout)
  const int srow = ((w >> 1) << 4) + (l >> 2);
  const int skx = ((w & 1) << 5) + ((((l & 3) << 3)) ^ (((l >> 5) & 1) << 4));
  const ushort* gA = Hf + (size_t)(mt * 256 + srow) * D_ + skx;
  const ushort* gB = Wf + (size_t)(nt * 256 + srow) * D_ + skx;

  // ds_read per-lane offset (ushorts): st_16x32 swizzled
  const int laneu =
      ((l & 15) << 5) + (((((l >> 4) << 4)) ^ (((l >> 3) & 1) << 5)) >> 1);
  const ushort* lA[2] = {&lds[(0 * 2 + wm) * 8192 + laneu],
                         &lds[(1 * 2 + wm) * 8192 + laneu]};
  const ushort* lB[2] = {
      &lds[BOFF + (0 * 2 + (wn >> 1)) * 8192 + (wn & 1) * 4096 + laneu],
      &lds[BOFF + (1 * 2 + (wn >> 1)) * 8192 + (wn & 1) * 4096 + laneu]};

  bf16x8 a0[4][2], a1[4][2], b0[2][2], b1[2][2];
  f32x4 acc[8][4] = {};

  // prologue: dbuf0 <- ktile 0 (A0,A1,B0,B1); dbuf1 <- ktile 1 (A0,A1)
  STAGE(AOFF, gA, 0, 0, 0);
  STAGE(AOFF, gA, 0, 1, 0);
  STAGE(BOFF, gB, 0, 0, 0);
  STAGE(BOFF, gB, 0, 1, 0);
  STAGE(AOFF, gA, 1, 0, 1);
  STAGE(AOFF, gA, 1, 1, 1);
  WAITV4;  // dbuf0 fully landed (own loads); barrier makes it collective
  phase_barrier();

#pragma unroll 1
  for (int i = 0; i < 8; ++i) {
    const int t1 = 2 * i + 1, t2 = 2 * i + 2, t3 = 2 * i + 3;
    const bool more = (i < 7);
    // ---- PH1: read A(mh0)+B(nh0) of dbuf0; stage dbuf1.B0 <- t1
    LD_A(a0, lA[0], 0);
    LD_B(b0, lB[0], 0);
    STAGE(BOFF, gB, 1, 0, t1);
    phase_barrier();
    Q_MFMA(a0, b0, 0, 0);
    phase_barrier();
    // ---- PH2: read A(mh1); stage dbuf1.B1 <- t1
    LD_A(a1, lA[0], 4);
    STAGE(BOFF, gB, 1, 1, t1);
    phase_barrier();
    Q_MFMA(a1, b0, 4, 0);
    phase_barrier();
    // ---- PH3: read B(nh1); stage dbuf0.A0 <- t2
    LD_B(b1, lB[0], 2);
    if (more) STAGE(AOFF, gA, 0, 0, t2);
    phase_barrier();
    Q_MFMA(a0, b1, 0, 2);
    phase_barrier();
    // ---- PH4: stage dbuf0.A1 <- t2; vmcnt before end barrier
    if (more) STAGE(AOFF, gA, 0, 1, t2);
    phase_barrier();
    Q_MFMA(a1, b1, 4, 2);
    if (more) { WAITV4; } else { WAITV0; }
    phase_barrier();
    // ---- PH5: dbuf1 K-tile; stage dbuf0.B0 <- t2
    LD_A(a0, lA[1], 0);
    LD_B(b0, lB[1], 0);
    if (more) STAGE(BOFF, gB, 0, 0, t2);
    phase_barrier();
    Q_MFMA(a0, b0, 0, 0);
    phase_barrier();
    // ---- PH6: stage dbuf0.B1 <- t2
    LD_A(a1, lA[1], 4);
    if (more) STAGE(BOFF, gB, 0, 1, t2);
    phase_barrier();
    Q_MFMA(a1, b0, 4, 0);
    phase_barrier();
    // ---- PH7: stage dbuf1.A0 <- t3
    LD_B(b1, lB[1], 2);
    if (more) STAGE(AOFF, gA, 1, 0, t3);
    phase_barrier();
    Q_MFMA(a0, b1, 0, 2);
    phase_barrier();
    // ---- PH8: stage dbuf1.A1 <- t3; vmcnt(4)
    if (more) STAGE(AOFF, gA, 1, 1, t3);
    phase_barrier();
    Q_MFMA(a1, b1, 4, 2);
    if (more) WAITV4;
    phase_barrier();
  }

  // epilogue: C layout col = lane&15, row = (lane>>4)*4 + q
  const float* bp = bias + f * V_;
  const int orow0 = mt * 256 + wm * 128 + ((l >> 4) << 2);
  const int ocol0 = nt * 256 + wn * 64 + (l & 15);
#pragma unroll
  for (int fi = 0; fi < 8; ++fi) {
#pragma unroll
    for (int fn = 0; fn < 4; ++fn) {
      int col = ocol0 + fn * 16;
      if (col < V_) {
        float bb = bp[col];
        int row = orow0 + fi * 16;
        float* op = out + (size_t)row * (F_ * V_) + (size_t)f * V_ + col;
#pragma unroll
        for (int q = 0; q < 4; ++q)
          op[(size_t)q * (F_ * V_)] = acc[fi][fn][q] + bb;
      }
    }
  }
}

// ---------------------------------------------------------------------------
extern "C" void kernel_launch(void* const* d_in, const int* in_sizes, int n_in,
                              void* d_out, int out_size, void* d_ws,
                              size_t ws_size, hipStream_t stream) {
  const float* emb = (const float*)d_in[0];     // (B, D)
  const int* feats = (const int*)d_in[1];       // (B, F)
  const float* tables = (const float*)d_in[2];  // (F, V, D)
  const float* gamma = (const float*)d_in[3];   // (D,)
  const float* beta = (const float*)d_in[4];    // (D,)
  const float* W = (const float*)d_in[5];       // (F, D, V)
  const float* bias = (const float*)d_in[6];    // (F, V)
  float* out = (float*)d_out;                   // (B, F, V)

  char* ws = (char*)d_ws;
  __hip_bfloat16* Hbuf = (__hip_bfloat16*)ws;  // F*B*D*2 = 64 MiB
  __hip_bfloat16* Wtbuf =
      (__hip_bfloat16*)(ws + (size_t)F_ * B_ * D_ * 2);  // F*VP*D*2 = 16 MiB

  transpose_w<<<dim3(D_ / 32, VP / 32, F_), dim3(32, 8), 0, stream>>>(W, Wtbuf);
  fuse_h<<<dim3(B_), dim3(256), 0, stream>>>(emb, feats, tables, gamma, beta,
                                             Hbuf);
  gemm_hw<<<dim3((B_ / 256) * (VP / 256) * F_), dim3(512), 0, stream>>>(
      (const ushort*)Hbuf, (const ushort*)Wtbuf, bias, out);
}

// Round 3
// 135.776 us; speedup vs baseline: 1.2500x; 1.0049x over previous
//
#include <hip/hip_runtime.h>
#include <hip/hip_bf16.h>

#define B_ 4096
#define F_ 8
#define V_ 1000
#define D_ 1024
#define VP 1024

typedef __bf16 bf16x8 __attribute__((ext_vector_type(8)));
typedef float f32x4 __attribute__((ext_vector_type(4)));

__device__ __forceinline__ void gload_lds16(const void* g, void* l) {
  __builtin_amdgcn_global_load_lds(
      (const __attribute__((address_space(1))) void*)g,
      (__attribute__((address_space(3))) void*)l, 16, 0, 0);
}

// ---------------------------------------------------------------------------
// Kernel 0: W (F,D,V) f32 -> Wt (F, VP, D) bf16, zero-padded v in [V,VP)
// ---------------------------------------------------------------------------
__global__ __launch_bounds__(256) void transpose_w(
    const float* __restrict__ W, __hip_bfloat16* __restrict__ Wt) {
  __shared__ float tile[32][33];
  const int f = blockIdx.z;
  const int k0 = blockIdx.x * 32;
  const int v0 = blockIdx.y * 32;
  const int tx = threadIdx.x;
  const int ty = threadIdx.y;
  const float* Wf = W + (size_t)f * D_ * V_;
#pragma unroll
  for (int i = 0; i < 4; ++i) {
    int k = k0 + ty + i * 8;
    int v = v0 + tx;
    tile[ty + i * 8][tx] = (v < V_) ? Wf[k * V_ + v] : 0.0f;
  }
  __syncthreads();
  __hip_bfloat16* Wtf = Wt + (size_t)f * VP * D_;
#pragma unroll
  for (int i = 0; i < 4; ++i) {
    int v = v0 + ty + i * 8;
    int k = k0 + tx;
    Wtf[v * D_ + k] = __float2bfloat16(tile[tx][ty + i * 8]);
  }
}

// ---------------------------------------------------------------------------
// Kernel 1: fused gather + cumsum + LayerNorm + exact gelu -> H (F, B, D) bf16
// ---------------------------------------------------------------------------
__global__ __launch_bounds__(256) void fuse_h(
    const float* __restrict__ emb, const int* __restrict__ feats,
    const float* __restrict__ tables, const float* __restrict__ gamma,
    const float* __restrict__ beta, __hip_bfloat16* __restrict__ H) {
  const int b = blockIdx.x;
  const int t = threadIdx.x;
  const int d = t * 4;
  const int wave = t >> 6, lane = t & 63;

  float s[4];
  {
    float4 v = *reinterpret_cast<const float4*>(&emb[(size_t)b * D_ + d]);
    s[0] = v.x; s[1] = v.y; s[2] = v.z; s[3] = v.w;
  }
  float gm[4], bt[4];
  {
    float4 g = *reinterpret_cast<const float4*>(&gamma[d]);
    float4 bb = *reinterpret_cast<const float4*>(&beta[d]);
    gm[0] = g.x; gm[1] = g.y; gm[2] = g.z; gm[3] = g.w;
    bt[0] = bb.x; bt[1] = bb.y; bt[2] = bb.z; bt[3] = bb.w;
  }
  __shared__ float red[4][2];

  for (int f = 0; f < F_; ++f) {
    float sum = s[0] + s[1] + s[2] + s[3];
    float ssq = s[0] * s[0] + s[1] * s[1] + s[2] * s[2] + s[3] * s[3];
#pragma unroll
    for (int off = 32; off > 0; off >>= 1) {
      sum += __shfl_xor(sum, off, 64);
      ssq += __shfl_xor(ssq, off, 64);
    }
    if (lane == 0) { red[wave][0] = sum; red[wave][1] = ssq; }
    __syncthreads();
    sum = red[0][0] + red[1][0] + red[2][0] + red[3][0];
    ssq = red[0][1] + red[1][1] + red[2][1] + red[3][1];
    __syncthreads();

    const float mu = sum * (1.0f / D_);
    const float var = ssq * (1.0f / D_) - mu * mu;
    const float rstd = rsqrtf(var + 1e-5f);

    __hip_bfloat16 hb[4];
#pragma unroll
    for (int j = 0; j < 4; ++j) {
      float x = (s[j] - mu) * rstd * gm[j] + bt[j];
      float g = 0.5f * x * (1.0f + erff(x * 0.70710678118654752f));
      hb[j] = __float2bfloat16(g);
    }
    *reinterpret_cast<uint2*>(&H[(size_t)f * (B_ * D_) + (size_t)b * D_ + d]) =
        *reinterpret_cast<const uint2*>(hb);

    if (f < F_ - 1) {
      int feat = feats[b * F_ + f];
      const float* row = tables + ((size_t)f * V_ + feat) * D_;
      float4 tv = *reinterpret_cast<const float4*>(&row[d]);
      s[0] += tv.x; s[1] += tv.y; s[2] += tv.z; s[3] += tv.w;
    }
  }
}

// ---------------------------------------------------------------------------
// Kernel 2: 256x256 8-phase GEMM (m201 template), BK=64, 8 waves (2Mx4N),
// dbuf LDS + st_16x32-style swizzle via pre-swizzled global source, ONE raw
// s_barrier per phase, counted vmcnt(6) only at phases 4 and 8.
// out[b, f, v] = sum_k H[f,b,k] * Wt[f,v,k] + bias[f,v]
// ---------------------------------------------------------------------------
#define AOFF 0
#define BOFF 32768

#define STAGE(OPB, GB, DBUF, HALF, KT)                                        \
  do {                                                                        \
    const ushort* _g = (GB) + (size_t)(HALF) * (128 * D_) + (size_t)(KT) * 64;\
    ushort* _l = &lds[(OPB) + ((DBUF)*2 + (HALF)) * 8192 + w * 512];          \
    gload_lds16(_g, _l);                                                      \
    gload_lds16(_g + 64 * D_, _l + 4096);                                     \
  } while (0)

#define LD_A(DST, LBASE, FIOFF)                                               \
  _Pragma("unroll") for (int _fj = 0; _fj < 4; ++_fj)                         \
  _Pragma("unroll") for (int _ks = 0; _ks < 2; ++_ks)                         \
      DST[_fj][_ks] = *reinterpret_cast<const bf16x8*>(                       \
          (LBASE) + ((((FIOFF) + _fj) * 2 + _ks) * 512));

#define LD_B(DST, LBASE, NFOFF)                                               \
  _Pragma("unroll") for (int _fn = 0; _fn < 2; ++_fn)                         \
  _Pragma("unroll") for (int _ks = 0; _ks < 2; ++_ks)                         \
      DST[_fn][_ks] = *reinterpret_cast<const bf16x8*>(                       \
          (LBASE) + ((((NFOFF) + _fn) * 2 + _ks) * 512));

#define Q_MFMA(AF, BF, R0, C0)                                                \
  do {                                                                        \
    __builtin_amdgcn_s_setprio(1);                                            \
    _Pragma("unroll") for (int _fj = 0; _fj < 4; ++_fj)                       \
    _Pragma("unroll") for (int _fn = 0; _fn < 2; ++_fn)                       \
    _Pragma("unroll") for (int _ks = 0; _ks < 2; ++_ks)                       \
        acc[(R0) + _fj][(C0) + _fn] =                                         \
            __builtin_amdgcn_mfma_f32_16x16x32_bf16(                          \
                AF[_fj][_ks], BF[_fn][_ks], acc[(R0) + _fj][(C0) + _fn],      \
                0, 0, 0);                                                     \
    __builtin_amdgcn_s_setprio(0);                                            \
  } while (0)

// one raw barrier per phase; empty asm = compiler-level code-motion fence only
#define PHB                                                                   \
  do {                                                                        \
    asm volatile("" ::: "memory");                                            \
    __builtin_amdgcn_s_barrier();                                             \
    asm volatile("" ::: "memory");                                            \
  } while (0)

#define WAITV6 asm volatile("s_waitcnt vmcnt(6)" ::: "memory")
#define WAITV0 asm volatile("s_waitcnt vmcnt(0)" ::: "memory")

__global__ __launch_bounds__(512, 2) void gemm_hw(
    const ushort* __restrict__ H,    // (F, B, D) bf16
    const ushort* __restrict__ Wt,   // (F, VP, D) bf16
    const float* __restrict__ bias,  // (F, V)
    float* __restrict__ out) {       // (B, F, V)
  __shared__ ushort lds[65536];  // 128 KiB

  // bijective XCD swizzle: nwg=512, 512%8==0
  const int bid = blockIdx.x;
  const int swz = (bid & 7) * 64 + (bid >> 3);
  const int f = swz >> 6;
  const int r = swz & 63;
  const int mt = r >> 2, nt = r & 3;

  const int t = threadIdx.x;
  const int w = t >> 6, l = t & 63;
  const int wm = w >> 2;   // 0..1 (M)
  const int wn = w & 3;    // 0..3 (N)

  const ushort* Hf = H + (size_t)f * (B_ * D_);
  const ushort* Wf = Wt + (size_t)f * (VP * D_);

  // staging global source (pre-swizzled so linear LDS write = swizzled layout)
  const int srow = ((w >> 1) << 4) + (l >> 2);
  const int skx = ((w & 1) << 5) + ((((l & 3) << 3)) ^ (((l >> 5) & 1) << 4));
  const ushort* gA = Hf + (size_t)(mt * 256 + srow) * D_ + skx;
  const ushort* gB = Wf + (size_t)(nt * 256 + srow) * D_ + skx;

  // ds_read per-lane offset (ushorts): same swizzle on read side
  const int laneu =
      ((l & 15) << 5) + (((((l >> 4) << 4)) ^ (((l >> 3) & 1) << 5)) >> 1);
  const ushort* lA[2] = {&lds[(0 * 2 + wm) * 8192 + laneu],
                         &lds[(1 * 2 + wm) * 8192 + laneu]};
  const ushort* lB[2] = {
      &lds[BOFF + (0 * 2 + (wn >> 1)) * 8192 + (wn & 1) * 4096 + laneu],
      &lds[BOFF + (1 * 2 + (wn >> 1)) * 8192 + (wn & 1) * 4096 + laneu]};

  bf16x8 a0[4][2], a1[4][2], b0[2][2], b1[2][2];
  f32x4 acc[8][4] = {};

  // prologue: T0 full + T1 {A0,A1,B0}; B1(T1) is staged at PH1 of iter 0.
  STAGE(AOFF, gA, 0, 0, 0);
  STAGE(AOFF, gA, 0, 1, 0);
  STAGE(BOFF, gB, 0, 0, 0);
  STAGE(BOFF, gB, 0, 1, 0);
  STAGE(AOFF, gA, 1, 0, 1);
  STAGE(AOFF, gA, 1, 1, 1);
  STAGE(BOFF, gB, 1, 0, 1);
  WAITV6;  // 14 issued, keep 6 -> drains exactly T0's 8 loads
  PHB;

#pragma unroll 1
  for (int i = 0; i < 8; ++i) {
    const int t1 = 2 * i + 1, t2 = 2 * i + 2, t3 = 2 * i + 3;
    const bool more = (i < 7);
    // ---- PH1: read a0,b0(T0); stage B1(T1)
    LD_A(a0, lA[0], 0);
    LD_B(b0, lB[0], 0);
    STAGE(BOFF, gB, 1, 1, t1);
    PHB;
    Q_MFMA(a0, b0, 0, 0);
    // ---- PH2: read a1(T0); stage A0(T2)
    LD_A(a1, lA[0], 4);
    if (more) STAGE(AOFF, gA, 0, 0, t2);
    PHB;
    Q_MFMA(a1, b0, 4, 0);
    // ---- PH3: read b1(T0); stage A1(T2)
    LD_B(b1, lB[0], 2);
    if (more) STAGE(AOFF, gA, 0, 1, t2);
    PHB;
    Q_MFMA(a0, b1, 0, 2);
    // ---- PH4: stage B0(T2); counted wait (T1 must be fully landed)
    if (more) STAGE(BOFF, gB, 0, 0, t2);
    if (more) { WAITV6; } else { WAITV0; }
    PHB;
    Q_MFMA(a1, b1, 4, 2);
    // ---- PH5: read a0,b0(T1); stage B1(T2)
    LD_A(a0, lA[1], 0);
    LD_B(b0, lB[1], 0);
    if (more) STAGE(BOFF, gB, 0, 1, t2);
    PHB;
    Q_MFMA(a0, b0, 0, 0);
    // ---- PH6: read a1(T1); stage A0(T3)
    LD_A(a1, lA[1], 4);
    if (more) STAGE(AOFF, gA, 1, 0, t3);
    PHB;
    Q_MFMA(a1, b0, 4, 0);
    // ---- PH7: read b1(T1); stage A1(T3)
    LD_B(b1, lB[1], 2);
    if (more) STAGE(AOFF, gA, 1, 1, t3);
    PHB;
    Q_MFMA(a0, b1, 0, 2);
    // ---- PH8: stage B0(T3); counted wait (T2 must be fully landed)
    if (more) {
      STAGE(BOFF, gB, 1, 0, t3);
      WAITV6;
    }
    PHB;
    Q_MFMA(a1, b1, 4, 2);
  }

  // epilogue: C layout col = lane&15, row = (lane>>4)*4 + q
  const float* bp = bias + f * V_;
  const int orow0 = mt * 256 + wm * 128 + ((l >> 4) << 2);
  const int ocol0 = nt * 256 + wn * 64 + (l & 15);
#pragma unroll
  for (int fi = 0; fi < 8; ++fi) {
#pragma unroll
    for (int fn = 0; fn < 4; ++fn) {
      int col = ocol0 + fn * 16;
      if (col < V_) {
        float bb = bp[col];
        int row = orow0 + fi * 16;
        float* op = out + (size_t)row * (F_ * V_) + (size_t)f * V_ + col;
#pragma unroll
        for (int q = 0; q < 4; ++q)
          op[(size_t)q * (F_ * V_)] = acc[fi][fn][q] + bb;
      }
    }
  }
}

// ---------------------------------------------------------------------------
extern "C" void kernel_launch(void* const* d_in, const int* in_sizes, int n_in,
                              void* d_out, int out_size, void* d_ws,
                              size_t ws_size, hipStream_t stream) {
  const float* emb = (const float*)d_in[0];     // (B, D)
  const int* feats = (const int*)d_in[1];       // (B, F)
  const float* tables = (const float*)d_in[2];  // (F, V, D)
  const float* gamma = (const float*)d_in[3];   // (D,)
  const float* beta = (const float*)d_in[4];    // (D,)
  const float* W = (const float*)d_in[5];       // (F, D, V)
  const float* bias = (const float*)d_in[6];    // (F, V)
  float* out = (float*)d_out;                   // (B, F, V)

  char* ws = (char*)d_ws;
  __hip_bfloat16* Hbuf = (__hip_bfloat16*)ws;  // F*B*D*2 = 64 MiB
  __hip_bfloat16* Wtbuf =
      (__hip_bfloat16*)(ws + (size_t)F_ * B_ * D_ * 2);  // F*VP*D*2 = 16 MiB

  transpose_w<<<dim3(D_ / 32, VP / 32, F_), dim3(32, 8), 0, stream>>>(W, Wtbuf);
  fuse_h<<<dim3(B_), dim3(256), 0, stream>>>(emb, feats, tables, gamma, beta,
                                             Hbuf);
  gemm_hw<<<dim3((B_ / 256) * (VP / 256) * F_), dim3(512), 0, stream>>>(
      (const ushort*)Hbuf, (const ushort*)Wtbuf, bias, out);
}

// Round 4
// 135.679 us; speedup vs baseline: 1.2509x; 1.0007x over previous
//
#include <hip/hip_runtime.h>
#include <hip/hip_bf16.h>

#define B_ 4096
#define F_ 8
#define V_ 1000
#define D_ 1024
#define VP 1024

typedef __bf16 bf16x8 __attribute__((ext_vector_type(8)));
typedef float f32x4 __attribute__((ext_vector_type(4)));

__device__ __forceinline__ void gload_lds16(const void* g, void* l) {
  __builtin_amdgcn_global_load_lds(
      (const __attribute__((address_space(1))) void*)g,
      (__attribute__((address_space(3))) void*)l, 16, 0, 0);
}

// ---------------------------------------------------------------------------
// Kernel 0: W (F,D,V) f32 -> Wt (F, VP, D) bf16, zero-padded v in [V,VP)
// ---------------------------------------------------------------------------
__global__ __launch_bounds__(256) void transpose_w(
    const float* __restrict__ W, __hip_bfloat16* __restrict__ Wt) {
  __shared__ float tile[32][33];
  const int f = blockIdx.z;
  const int k0 = blockIdx.x * 32;
  const int v0 = blockIdx.y * 32;
  const int tx = threadIdx.x;
  const int ty = threadIdx.y;
  const float* Wf = W + (size_t)f * D_ * V_;
#pragma unroll
  for (int i = 0; i < 4; ++i) {
    int k = k0 + ty + i * 8;
    int v = v0 + tx;
    tile[ty + i * 8][tx] = (v < V_) ? Wf[k * V_ + v] : 0.0f;
  }
  __syncthreads();
  __hip_bfloat16* Wtf = Wt + (size_t)f * VP * D_;
#pragma unroll
  for (int i = 0; i < 4; ++i) {
    int v = v0 + ty + i * 8;
    int k = k0 + tx;
    Wtf[v * D_ + k] = __float2bfloat16(tile[tx][ty + i * 8]);
  }
}

// ---------------------------------------------------------------------------
// Kernel 1: fused gather + cumsum + LayerNorm + exact gelu -> H (F, B, D) bf16
// single __syncthreads per f via double-buffered reduction scratch
// ---------------------------------------------------------------------------
__global__ __launch_bounds__(256) void fuse_h(
    const float* __restrict__ emb, const int* __restrict__ feats,
    const float* __restrict__ tables, const float* __restrict__ gamma,
    const float* __restrict__ beta, __hip_bfloat16* __restrict__ H) {
  const int b = blockIdx.x;
  const int t = threadIdx.x;
  const int d = t * 4;
  const int wave = t >> 6, lane = t & 63;

  float s[4];
  {
    float4 v = *reinterpret_cast<const float4*>(&emb[(size_t)b * D_ + d]);
    s[0] = v.x; s[1] = v.y; s[2] = v.z; s[3] = v.w;
  }
  float gm[4], bt[4];
  {
    float4 g = *reinterpret_cast<const float4*>(&gamma[d]);
    float4 bb = *reinterpret_cast<const float4*>(&beta[d]);
    gm[0] = g.x; gm[1] = g.y; gm[2] = g.z; gm[3] = g.w;
    bt[0] = bb.x; bt[1] = bb.y; bt[2] = bb.z; bt[3] = bb.w;
  }
  __shared__ float red[2][4][2];

  for (int f = 0; f < F_; ++f) {
    float sum = s[0] + s[1] + s[2] + s[3];
    float ssq = s[0] * s[0] + s[1] * s[1] + s[2] * s[2] + s[3] * s[3];
#pragma unroll
    for (int off = 32; off > 0; off >>= 1) {
      sum += __shfl_xor(sum, off, 64);
      ssq += __shfl_xor(ssq, off, 64);
    }
    const int pb = f & 1;
    if (lane == 0) { red[pb][wave][0] = sum; red[pb][wave][1] = ssq; }
    __syncthreads();
    sum = red[pb][0][0] + red[pb][1][0] + red[pb][2][0] + red[pb][3][0];
    ssq = red[pb][0][1] + red[pb][1][1] + red[pb][2][1] + red[pb][3][1];

    const float mu = sum * (1.0f / D_);
    const float var = ssq * (1.0f / D_) - mu * mu;
    const float rstd = rsqrtf(var + 1e-5f);

    __hip_bfloat16 hb[4];
#pragma unroll
    for (int j = 0; j < 4; ++j) {
      float x = (s[j] - mu) * rstd * gm[j] + bt[j];
      float g = 0.5f * x * (1.0f + erff(x * 0.70710678118654752f));
      hb[j] = __float2bfloat16(g);
    }
    *reinterpret_cast<uint2*>(&H[(size_t)f * (B_ * D_) + (size_t)b * D_ + d]) =
        *reinterpret_cast<const uint2*>(hb);

    if (f < F_ - 1) {
      int feat = feats[b * F_ + f];
      const float* row = tables + ((size_t)f * V_ + feat) * D_;
      float4 tv = *reinterpret_cast<const float4*>(&row[d]);
      s[0] += tv.x; s[1] += tv.y; s[2] += tv.z; s[3] += tv.w;
    }
  }
}

// ---------------------------------------------------------------------------
// Kernel 2: 256x256 8-phase GEMM, BK=64, 8 waves (2Mx4N), dbuf LDS.
// Fragments are ds_read ONE PHASE AHEAD of their MFMA (counted lgkm waits
// emerge from compiler), so the LDS pipe drains during the MFMA burst.
// Phase = {STAGE; [vmcnt]; barrier; reads(p+1); sched_barrier; MFMA(p)}.
// ---------------------------------------------------------------------------
#define AOFF 0
#define BOFF 32768

#define STAGE(OPB, GB, DBUF, HALF, KT)                                        \
  do {                                                                        \
    const ushort* _g = (GB) + (size_t)(HALF) * (128 * D_) + (size_t)(KT) * 64;\
    ushort* _l = &lds[(OPB) + ((DBUF)*2 + (HALF)) * 8192 + w * 512];          \
    gload_lds16(_g, _l);                                                      \
    gload_lds16(_g + 64 * D_, _l + 4096);                                     \
  } while (0)

#define LD_A(DST, LBASE, FIOFF)                                               \
  _Pragma("unroll") for (int _fj = 0; _fj < 4; ++_fj)                         \
  _Pragma("unroll") for (int _ks = 0; _ks < 2; ++_ks)                         \
      DST[_fj][_ks] = *reinterpret_cast<const bf16x8*>(                       \
          (LBASE) + ((((FIOFF) + _fj) * 2 + _ks) * 512));

#define LD_B(DST, LBASE, NFOFF)                                               \
  _Pragma("unroll") for (int _fn = 0; _fn < 2; ++_fn)                         \
  _Pragma("unroll") for (int _ks = 0; _ks < 2; ++_ks)                         \
      DST[_fn][_ks] = *reinterpret_cast<const bf16x8*>(                       \
          (LBASE) + ((((NFOFF) + _fn) * 2 + _ks) * 512));

#define Q_MFMA(AF, BF, R0, C0)                                                \
  do {                                                                        \
    __builtin_amdgcn_s_setprio(1);                                            \
    _Pragma("unroll") for (int _fj = 0; _fj < 4; ++_fj)                       \
    _Pragma("unroll") for (int _fn = 0; _fn < 2; ++_fn)                       \
    _Pragma("unroll") for (int _ks = 0; _ks < 2; ++_ks)                       \
        acc[(R0) + _fj][(C0) + _fn] =                                         \
            __builtin_amdgcn_mfma_f32_16x16x32_bf16(                          \
                AF[_fj][_ks], BF[_fn][_ks], acc[(R0) + _fj][(C0) + _fn],      \
                0, 0, 0);                                                     \
    __builtin_amdgcn_s_setprio(0);                                            \
  } while (0)

#define PHB                                                                   \
  do {                                                                        \
    asm volatile("" ::: "memory");                                            \
    __builtin_amdgcn_s_barrier();                                             \
    asm volatile("" ::: "memory");                                            \
  } while (0)

#define SB0 __builtin_amdgcn_sched_barrier(0)
#define WAITV6 asm volatile("s_waitcnt vmcnt(6)" ::: "memory")
#define WAITV0 asm volatile("s_waitcnt vmcnt(0)" ::: "memory")

__global__ __launch_bounds__(512, 2) void gemm_hw(
    const ushort* __restrict__ H,    // (F, B, D) bf16
    const ushort* __restrict__ Wt,   // (F, VP, D) bf16
    const float* __restrict__ bias,  // (F, V)
    float* __restrict__ out) {       // (B, F, V)
  __shared__ ushort lds[65536];  // 128 KiB

  // bijective XCD swizzle: nwg=512, 512%8==0
  const int bid = blockIdx.x;
  const int swz = (bid & 7) * 64 + (bid >> 3);
  const int f = swz >> 6;
  const int r = swz & 63;
  const int mt = r >> 2, nt = r & 3;

  const int t = threadIdx.x;
  const int w = t >> 6, l = t & 63;
  const int wm = w >> 2;   // 0..1 (M)
  const int wn = w & 3;    // 0..3 (N)

  const ushort* Hf = H + (size_t)f * (B_ * D_);
  const ushort* Wf = Wt + (size_t)f * (VP * D_);

  // staging global source (pre-swizzled so linear LDS write = swizzled layout)
  const int srow = ((w >> 1) << 4) + (l >> 2);
  const int skx = ((w & 1) << 5) + ((((l & 3) << 3)) ^ (((l >> 5) & 1) << 4));
  const ushort* gA = Hf + (size_t)(mt * 256 + srow) * D_ + skx;
  const ushort* gB = Wf + (size_t)(nt * 256 + srow) * D_ + skx;

  // ds_read per-lane offset (ushorts): same swizzle on read side
  const int laneu =
      ((l & 15) << 5) + (((((l >> 4) << 4)) ^ (((l >> 3) & 1) << 5)) >> 1);
  const ushort* lA[2] = {&lds[(0 * 2 + wm) * 8192 + laneu],
                         &lds[(1 * 2 + wm) * 8192 + laneu]};
  const ushort* lB[2] = {
      &lds[BOFF + (0 * 2 + (wn >> 1)) * 8192 + (wn & 1) * 4096 + laneu],
      &lds[BOFF + (1 * 2 + (wn >> 1)) * 8192 + (wn & 1) * 4096 + laneu]};

  bf16x8 a0[4][2], a1[4][2], b0[2][2], b1[2][2];
  f32x4 acc[8][4] = {};

  // prologue: T0 full + T1 {A0,A1,B0}; B1(T1) staged at PH1 of iter 0.
  STAGE(AOFF, gA, 0, 0, 0);
  STAGE(AOFF, gA, 0, 1, 0);
  STAGE(BOFF, gB, 0, 0, 0);
  STAGE(BOFF, gB, 0, 1, 0);
  STAGE(AOFF, gA, 1, 0, 1);
  STAGE(AOFF, gA, 1, 1, 1);
  STAGE(BOFF, gB, 1, 0, 1);
  WAITV6;  // 14 issued, keep 6 -> drains exactly T0's 8 loads
  PHB;
  // initial fragment reads for PH1's MFMA
  LD_A(a0, lA[0], 0);
  LD_B(b0, lB[0], 0);
  SB0;

#pragma unroll 1
  for (int i = 0; i < 8; ++i) {
    const int t1 = 2 * i + 1, t2 = 2 * i + 2, t3 = 2 * i + 3;
    const bool more = (i < 7);
    // ---- PH1: stage B1(T1); reads a1(T0); MFMA a0*b0
    STAGE(BOFF, gB, 1, 1, t1);
    PHB;
    LD_A(a1, lA[0], 4);
    SB0;
    Q_MFMA(a0, b0, 0, 0);
    // ---- PH2: stage A0(T2); reads b1(T0); MFMA a1*b0
    if (more) STAGE(AOFF, gA, 0, 0, t2);
    PHB;
    LD_B(b1, lB[0], 2);
    SB0;
    Q_MFMA(a1, b0, 4, 0);
    // ---- PH3: stage A1(T2); MFMA a0*b1
    if (more) STAGE(AOFF, gA, 0, 1, t2);
    PHB;
    SB0;
    Q_MFMA(a0, b1, 0, 2);
    // ---- PH4: stage B0(T2); vmcnt; reads a0,b0(T1); MFMA a1*b1
    if (more) STAGE(BOFF, gB, 0, 0, t2);
    if (more) { WAITV6; } else { WAITV0; }
    PHB;
    LD_A(a0, lA[1], 0);
    LD_B(b0, lB[1], 0);
    SB0;
    Q_MFMA(a1, b1, 4, 2);
    // ---- PH5: stage B1(T2); reads a1(T1); MFMA a0*b0
    if (more) STAGE(BOFF, gB, 0, 1, t2);
    PHB;
    LD_A(a1, lA[1], 4);
    SB0;
    Q_MFMA(a0, b0, 0, 0);
    // ---- PH6: stage A0(T3); reads b1(T1); MFMA a1*b0
    if (more) STAGE(AOFF, gA, 1, 0, t3);
    PHB;
    LD_B(b1, lB[1], 2);
    SB0;
    Q_MFMA(a1, b0, 4, 0);
    // ---- PH7: stage A1(T3); MFMA a0*b1
    if (more) STAGE(AOFF, gA, 1, 1, t3);
    PHB;
    SB0;
    Q_MFMA(a0, b1, 0, 2);
    // ---- PH8: stage B0(T3); vmcnt; reads a0,b0(T2-next); MFMA a1*b1
    if (more) {
      STAGE(BOFF, gB, 1, 0, t3);
      WAITV6;
    }
    PHB;
    if (more) {
      LD_A(a0, lA[0], 0);
      LD_B(b0, lB[0], 0);
    }
    SB0;
    Q_MFMA(a1, b1, 4, 2);
  }

  // epilogue: C layout col = lane&15, row = (lane>>4)*4 + q
  const float* bp = bias + f * V_;
  const int orow0 = mt * 256 + wm * 128 + ((l >> 4) << 2);
  const int ocol0 = nt * 256 + wn * 64 + (l & 15);
#pragma unroll
  for (int fi = 0; fi < 8; ++fi) {
#pragma unroll
    for (int fn = 0; fn < 4; ++fn) {
      int col = ocol0 + fn * 16;
      if (col < V_) {
        float bb = bp[col];
        int row = orow0 + fi * 16;
        float* op = out + (size_t)row * (F_ * V_) + (size_t)f * V_ + col;
#pragma unroll
        for (int q = 0; q < 4; ++q)
          op[(size_t)q * (F_ * V_)] = acc[fi][fn][q] + bb;
      }
    }
  }
}

// ---------------------------------------------------------------------------
extern "C" void kernel_launch(void* const* d_in, const int* in_sizes, int n_in,
                              void* d_out, int out_size, void* d_ws,
                              size_t ws_size, hipStream_t stream) {
  const float* emb = (const float*)d_in[0];     // (B, D)
  const int* feats = (const int*)d_in[1];       // (B, F)
  const float* tables = (const float*)d_in[2];  // (F, V, D)
  const float* gamma = (const float*)d_in[3];   // (D,)
  const float* beta = (const float*)d_in[4];    // (D,)
  const float* W = (const float*)d_in[5];       // (F, D, V)
  const float* bias = (const float*)d_in[6];    // (F, V)
  float* out = (float*)d_out;                   // (B, F, V)

  char* ws = (char*)d_ws;
  __hip_bfloat16* Hbuf = (__hip_bfloat16*)ws;  // F*B*D*2 = 64 MiB
  __hip_bfloat16* Wtbuf =
      (__hip_bfloat16*)(ws + (size_t)F_ * B_ * D_ * 2);  // F*VP*D*2 = 16 MiB

  transpose_w<<<dim3(D_ / 32, VP / 32, F_), dim3(32, 8), 0, stream>>>(W, Wtbuf);
  fuse_h<<<dim3(B_), dim3(256), 0, stream>>>(emb, feats, tables, gamma, beta,
                                             Hbuf);
  gemm_hw<<<dim3((B_ / 256) * (VP / 256) * F_), dim3(512), 0, stream>>>(
      (const ushort*)Hbuf, (const ushort*)Wtbuf, bias, out);
}

// Round 5
// 134.462 us; speedup vs baseline: 1.2623x; 1.0090x over previous
//
#include <hip/hip_runtime.h>
#include <hip/hip_bf16.h>

#define B_ 4096
#define F_ 8
#define V_ 1000
#define D_ 1024
#define VP 1024

typedef __bf16 bf16x8 __attribute__((ext_vector_type(8)));
typedef float f32x4 __attribute__((ext_vector_type(4)));

__device__ __forceinline__ void gload_lds16(const void* g, void* l) {
  __builtin_amdgcn_global_load_lds(
      (const __attribute__((address_space(1))) void*)g,
      (__attribute__((address_space(3))) void*)l, 16, 0, 0);
}

// ---------------------------------------------------------------------------
// Kernel 0: W (F,D,V) f32 -> Wt (F, VP, D) bf16, zero-padded v in [V,VP)
// ---------------------------------------------------------------------------
__global__ __launch_bounds__(256) void transpose_w(
    const float* __restrict__ W, __hip_bfloat16* __restrict__ Wt) {
  __shared__ float tile[32][33];
  const int f = blockIdx.z;
  const int k0 = blockIdx.x * 32;
  const int v0 = blockIdx.y * 32;
  const int tx = threadIdx.x;
  const int ty = threadIdx.y;
  const float* Wf = W + (size_t)f * D_ * V_;
#pragma unroll
  for (int i = 0; i < 4; ++i) {
    int k = k0 + ty + i * 8;
    int v = v0 + tx;
    tile[ty + i * 8][tx] = (v < V_) ? Wf[k * V_ + v] : 0.0f;
  }
  __syncthreads();
  __hip_bfloat16* Wtf = Wt + (size_t)f * VP * D_;
#pragma unroll
  for (int i = 0; i < 4; ++i) {
    int v = v0 + ty + i * 8;
    int k = k0 + tx;
    Wtf[v * D_ + k] = __float2bfloat16(tile[tx][ty + i * 8]);
  }
}

// ---------------------------------------------------------------------------
// Kernel 1: fused gather + cumsum + LayerNorm + exact gelu -> H (F, B, D) bf16
// ---------------------------------------------------------------------------
__global__ __launch_bounds__(256) void fuse_h(
    const float* __restrict__ emb, const int* __restrict__ feats,
    const float* __restrict__ tables, const float* __restrict__ gamma,
    const float* __restrict__ beta, __hip_bfloat16* __restrict__ H) {
  const int b = blockIdx.x;
  const int t = threadIdx.x;
  const int d = t * 4;
  const int wave = t >> 6, lane = t & 63;

  float s[4];
  {
    float4 v = *reinterpret_cast<const float4*>(&emb[(size_t)b * D_ + d]);
    s[0] = v.x; s[1] = v.y; s[2] = v.z; s[3] = v.w;
  }
  float gm[4], bt[4];
  {
    float4 g = *reinterpret_cast<const float4*>(&gamma[d]);
    float4 bb = *reinterpret_cast<const float4*>(&beta[d]);
    gm[0] = g.x; gm[1] = g.y; gm[2] = g.z; gm[3] = g.w;
    bt[0] = bb.x; bt[1] = bb.y; bt[2] = bb.z; bt[3] = bb.w;
  }
  __shared__ float red[2][4][2];

  for (int f = 0; f < F_; ++f) {
    float sum = s[0] + s[1] + s[2] + s[3];
    float ssq = s[0] * s[0] + s[1] * s[1] + s[2] * s[2] + s[3] * s[3];
#pragma unroll
    for (int off = 32; off > 0; off >>= 1) {
      sum += __shfl_xor(sum, off, 64);
      ssq += __shfl_xor(ssq, off, 64);
    }
    const int pb = f & 1;
    if (lane == 0) { red[pb][wave][0] = sum; red[pb][wave][1] = ssq; }
    __syncthreads();
    sum = red[pb][0][0] + red[pb][1][0] + red[pb][2][0] + red[pb][3][0];
    ssq = red[pb][0][1] + red[pb][1][1] + red[pb][2][1] + red[pb][3][1];

    const float mu = sum * (1.0f / D_);
    const float var = ssq * (1.0f / D_) - mu * mu;
    const float rstd = rsqrtf(var + 1e-5f);

    __hip_bfloat16 hb[4];
#pragma unroll
    for (int j = 0; j < 4; ++j) {
      float x = (s[j] - mu) * rstd * gm[j] + bt[j];
      float g = 0.5f * x * (1.0f + erff(x * 0.70710678118654752f));
      hb[j] = __float2bfloat16(g);
    }
    *reinterpret_cast<uint2*>(&H[(size_t)f * (B_ * D_) + (size_t)b * D_ + d]) =
        *reinterpret_cast<const uint2*>(hb);

    if (f < F_ - 1) {
      int feat = feats[b * F_ + f];
      const float* row = tables + ((size_t)f * V_ + feat) * D_;
      float4 tv = *reinterpret_cast<const float4*>(&row[d]);
      s[0] += tv.x; s[1] += tv.y; s[2] += tv.z; s[3] += tv.w;
    }
  }
}

// ---------------------------------------------------------------------------
// Kernel 2: 256x256 8-phase GEMM, BK=64, 8 waves (2Mx4N), dbuf LDS.
// m201 discipline: plain s_barrier (no memory-clobber fences), bare counted
// s_waitcnt vmcnt(4) only at PH4/PH8 (before the barrier, so collective),
// bare lgkmcnt(0)+sched_barrier(0) before each MFMA cluster.
// Stage order guarantees >=1 barrier between a region's last ds_read and its
// overwrite: PH1 B0d1(T1) PH2 B1d1(T1) PH3 A0d0(T2) PH4 A1d0(T2) PH5 B0d0(T2)
// PH6 B1d0(T2) PH7 A0d1(T3) PH8 A1d1(T3).
// ---------------------------------------------------------------------------
#define AOFF 0
#define BOFF 32768

#define STAGE(OPB, GB, DBUF, HALF, KT)                                        \
  do {                                                                        \
    const ushort* _g = (GB) + (size_t)(HALF) * (128 * D_) + (size_t)(KT) * 64;\
    ushort* _l = &lds[(OPB) + ((DBUF)*2 + (HALF)) * 8192 + w * 512];          \
    gload_lds16(_g, _l);                                                      \
    gload_lds16(_g + 64 * D_, _l + 4096);                                     \
  } while (0)

#define LD_A(DST, LBASE, FIOFF)                                               \
  _Pragma("unroll") for (int _fj = 0; _fj < 4; ++_fj)                         \
  _Pragma("unroll") for (int _ks = 0; _ks < 2; ++_ks)                         \
      DST[_fj][_ks] = *reinterpret_cast<const bf16x8*>(                       \
          (LBASE) + ((((FIOFF) + _fj) * 2 + _ks) * 512));

#define LD_B(DST, LBASE, NFOFF)                                               \
  _Pragma("unroll") for (int _fn = 0; _fn < 2; ++_fn)                         \
  _Pragma("unroll") for (int _ks = 0; _ks < 2; ++_ks)                         \
      DST[_fn][_ks] = *reinterpret_cast<const bf16x8*>(                       \
          (LBASE) + ((((NFOFF) + _fn) * 2 + _ks) * 512));

#define Q_MFMA(AF, BF, R0, C0)                                                \
  do {                                                                        \
    __builtin_amdgcn_s_setprio(1);                                            \
    _Pragma("unroll") for (int _fj = 0; _fj < 4; ++_fj)                       \
    _Pragma("unroll") for (int _fn = 0; _fn < 2; ++_fn)                       \
    _Pragma("unroll") for (int _ks = 0; _ks < 2; ++_ks)                       \
        acc[(R0) + _fj][(C0) + _fn] =                                         \
            __builtin_amdgcn_mfma_f32_16x16x32_bf16(                          \
                AF[_fj][_ks], BF[_fn][_ks], acc[(R0) + _fj][(C0) + _fn],      \
                0, 0, 0);                                                     \
    __builtin_amdgcn_s_setprio(0);                                            \
  } while (0)

#define BAR __builtin_amdgcn_s_barrier()
#define SB0 __builtin_amdgcn_sched_barrier(0)
#define VM4 asm volatile("s_waitcnt vmcnt(4)")
#define VM0 asm volatile("s_waitcnt vmcnt(0)")
#define LG0 asm volatile("s_waitcnt lgkmcnt(0)")

__global__ __launch_bounds__(512, 2) void gemm_hw(
    const ushort* __restrict__ H,    // (F, B, D) bf16
    const ushort* __restrict__ Wt,   // (F, VP, D) bf16
    const float* __restrict__ bias,  // (F, V)
    float* __restrict__ out) {       // (B, F, V)
  __shared__ ushort lds[65536];  // 128 KiB

  // bijective XCD swizzle: nwg=512, 512%8==0
  const int bid = blockIdx.x;
  const int swz = (bid & 7) * 64 + (bid >> 3);
  const int f = swz >> 6;
  const int r = swz & 63;
  const int mt = r >> 2, nt = r & 3;

  const int t = threadIdx.x;
  const int w = t >> 6, l = t & 63;
  const int wm = w >> 2;   // 0..1 (M)
  const int wn = w & 3;    // 0..3 (N)

  const ushort* Hf = H + (size_t)f * (B_ * D_);
  const ushort* Wf = Wt + (size_t)f * (VP * D_);

  // staging global source (pre-swizzled so linear LDS write = swizzled layout)
  const int srow = ((w >> 1) << 4) + (l >> 2);
  const int skx = ((w & 1) << 5) + ((((l & 3) << 3)) ^ (((l >> 5) & 1) << 4));
  const ushort* gA = Hf + (size_t)(mt * 256 + srow) * D_ + skx;
  const ushort* gB = Wf + (size_t)(nt * 256 + srow) * D_ + skx;

  // ds_read per-lane offset (ushorts): same swizzle on read side
  const int laneu =
      ((l & 15) << 5) + (((((l >> 4) << 4)) ^ (((l >> 3) & 1) << 5)) >> 1);
  const ushort* lA[2] = {&lds[(0 * 2 + wm) * 8192 + laneu],
                         &lds[(1 * 2 + wm) * 8192 + laneu]};
  const ushort* lB[2] = {
      &lds[BOFF + (0 * 2 + (wn >> 1)) * 8192 + (wn & 1) * 4096 + laneu],
      &lds[BOFF + (1 * 2 + (wn >> 1)) * 8192 + (wn & 1) * 4096 + laneu]};

  bf16x8 a0[4][2], a1[4][2], b0[2][2], b1[2][2];
  f32x4 acc[8][4] = {};

  // prologue: dbuf0{A0,A1,B0,B1}(T0) then dbuf1{A0,A1}(T1) -> 12 loads.
  // vmcnt(4) drains the 8 T0 loads, leaves the 4 dbuf1.A(T1) in flight.
  STAGE(AOFF, gA, 0, 0, 0);
  STAGE(AOFF, gA, 0, 1, 0);
  STAGE(BOFF, gB, 0, 0, 0);
  STAGE(BOFF, gB, 0, 1, 0);
  STAGE(AOFF, gA, 1, 0, 1);
  STAGE(AOFF, gA, 1, 1, 1);
  VM4;
  BAR;

#pragma unroll 1
  for (int i = 0; i < 8; ++i) {
    const int t1 = 2 * i + 1, t2 = 2 * i + 2, t3 = 2 * i + 3;
    const bool more = (i < 7);
    // PH1: reads a0,b0(T0); stage d1.B0(T1)
    LD_A(a0, lA[0], 0);
    LD_B(b0, lB[0], 0);
    STAGE(BOFF, gB, 1, 0, t1);
    BAR;
    LG0;
    SB0;
    Q_MFMA(a0, b0, 0, 0);
    // PH2: reads a1(T0); stage d1.B1(T1)
    LD_A(a1, lA[0], 4);
    STAGE(BOFF, gB, 1, 1, t1);
    BAR;
    LG0;
    SB0;
    Q_MFMA(a1, b0, 4, 0);
    // PH3: reads b1(T0); stage d0.A0(T2)  [d0.A last read PH2]
    LD_B(b1, lB[0], 2);
    if (more) STAGE(AOFF, gA, 0, 0, t2);
    BAR;
    LG0;
    SB0;
    Q_MFMA(a0, b1, 0, 2);
    // PH4: stage d0.A1(T2); vmcnt(4) collective -> dbuf1(T1) landed
    if (more) {
      STAGE(AOFF, gA, 0, 1, t2);
      VM4;
    } else {
      VM0;
    }
    BAR;
    SB0;
    Q_MFMA(a1, b1, 4, 2);
    // PH5: reads a0,b0(T1); stage d0.B0(T2)  [d0.B last read PH3]
    LD_A(a0, lA[1], 0);
    LD_B(b0, lB[1], 0);
    if (more) STAGE(BOFF, gB, 0, 0, t2);
    BAR;
    LG0;
    SB0;
    Q_MFMA(a0, b0, 0, 0);
    // PH6: reads a1(T1); stage d0.B1(T2)
    LD_A(a1, lA[1], 4);
    if (more) STAGE(BOFF, gB, 0, 1, t2);
    BAR;
    LG0;
    SB0;
    Q_MFMA(a1, b0, 4, 0);
    // PH7: reads b1(T1); stage d1.A0(T3)  [d1.A last read PH6]
    LD_B(b1, lB[1], 2);
    if (more) STAGE(AOFF, gA, 1, 0, t3);
    BAR;
    LG0;
    SB0;
    Q_MFMA(a0, b1, 0, 2);
    // PH8: stage d1.A1(T3); vmcnt(4) collective -> dbuf0(T2) landed
    if (more) {
      STAGE(AOFF, gA, 1, 1, t3);
      VM4;
    }
    BAR;
    SB0;
    Q_MFMA(a1, b1, 4, 2);
  }

  // epilogue: C layout col = lane&15, row = (lane>>4)*4 + q
  const float* bp = bias + f * V_;
  const int orow0 = mt * 256 + wm * 128 + ((l >> 4) << 2);
  const int ocol0 = nt * 256 + wn * 64 + (l & 15);
#pragma unroll
  for (int fi = 0; fi < 8; ++fi) {
#pragma unroll
    for (int fn = 0; fn < 4; ++fn) {
      int col = ocol0 + fn * 16;
      if (col < V_) {
        float bb = bp[col];
        int row = orow0 + fi * 16;
        float* op = out + (size_t)row * (F_ * V_) + (size_t)f * V_ + col;
#pragma unroll
        for (int q = 0; q < 4; ++q)
          op[(size_t)q * (F_ * V_)] = acc[fi][fn][q] + bb;
      }
    }
  }
}

// ---------------------------------------------------------------------------
extern "C" void kernel_launch(void* const* d_in, const int* in_sizes, int n_in,
                              void* d_out, int out_size, void* d_ws,
                              size_t ws_size, hipStream_t stream) {
  const float* emb = (const float*)d_in[0];     // (B, D)
  const int* feats = (const int*)d_in[1];       // (B, F)
  const float* tables = (const float*)d_in[2];  // (F, V, D)
  const float* gamma = (const float*)d_in[3];   // (D,)
  const float* beta = (const float*)d_in[4];    // (D,)
  const float* W = (const float*)d_in[5];       // (F, D, V)
  const float* bias = (const float*)d_in[6];    // (F, V)
  float* out = (float*)d_out;                   // (B, F, V)

  char* ws = (char*)d_ws;
  __hip_bfloat16* Hbuf = (__hip_bfloat16*)ws;  // F*B*D*2 = 64 MiB
  __hip_bfloat16* Wtbuf =
      (__hip_bfloat16*)(ws + (size_t)F_ * B_ * D_ * 2);  // F*VP*D*2 = 16 MiB

  transpose_w<<<dim3(D_ / 32, VP / 32, F_), dim3(32, 8), 0, stream>>>(W, Wtbuf);
  fuse_h<<<dim3(B_), dim3(256), 0, stream>>>(emb, feats, tables, gamma, beta,
                                             Hbuf);
  gemm_hw<<<dim3((B_ / 256) * (VP / 256) * F_), dim3(512), 0, stream>>>(
      (const ushort*)Hbuf, (const ushort*)Wtbuf, bias, out);
}